// Round 1
// baseline (272.876 us; speedup 1.0000x reference)
//
#include <hip/hip_runtime.h>

#define BB 4
#define CC 256
#define DD 32
#define SS 4096

typedef __bf16 bf16;
typedef __bf16 bf16x8 __attribute__((ext_vector_type(8)));
typedef __bf16 bf16x4 __attribute__((ext_vector_type(4)));
typedef float f32x4 __attribute__((ext_vector_type(4)));
typedef unsigned int u32;
typedef unsigned short u16;

// workspace layout (bf16 elements):
//  q:  [2][BB][SS][DD]  off 0         (pos-major, 32 d inner)
//  k:  [2][BB][SS][DD]  off 1048576
//  v:  [2][BB][CC][SS]  off 2097152   (c-major, pos inner)
//  wb: [320][CC]        off 10485760  (bf16 Wq|Wk|Wv stacked)
#define Q_OFF  0
#define K_OFF  1048576
#define V_OFF  2097152
#define WB_OFF 10485760

static __device__ __forceinline__ u32 pack2(float lo, float hi) {
    bf16 a = (bf16)lo, b = (bf16)hi;
    u16 ua = __builtin_bit_cast(u16, a), ub = __builtin_bit_cast(u16, b);
    return (u32)ua | ((u32)ub << 16);
}

// ------------------------------------------------- W fp32 -> bf16 [320][256]
__global__ __launch_bounds__(256) void convert_w_kernel(
    const float* __restrict__ Wq, const float* __restrict__ Wk,
    const float* __restrict__ Wv, bf16* __restrict__ wb)
{
    const int gid = blockIdx.x*256 + threadIdx.x;    // 40 blocks -> 10240
    const int idx = gid*8;
    const int o = idx >> 8, cc = idx & 255;
    const float* row = (o < 32) ? (Wq + (size_t)o*CC)
                     : (o < 64) ? (Wk + (size_t)(o-32)*CC)
                                : (Wv + (size_t)(o-64)*CC);
    const float4 a = *(const float4*)(row + cc);
    const float4 c = *(const float4*)(row + cc + 4);
    bf16x8 pk;
    pk[0]=(bf16)a.x; pk[1]=(bf16)a.y; pk[2]=(bf16)a.z; pk[3]=(bf16)a.w;
    pk[4]=(bf16)c.x; pk[5]=(bf16)c.y; pk[6]=(bf16)c.z; pk[7]=(bf16)c.w;
    *(bf16x8*)(wb + idx) = pk;
}

// ------------------------------------------------- fused q,k,v projection (MFMA)
// C[pos][o] = sum_cc X[cc][pos]*W[o][cc] + bias;  o: 0-31 q, 32-63 k, 64-319 v
// 32-pos tiles -> grid 1024 (4 blocks/CU). xT rows padded to 128 B with XOR
// chunk swizzle (conflict-free ds_read_b128). Staging by threads 0..127.
__global__ __launch_bounds__(256, 4) void proj_all_kernel(
    const float* __restrict__ x, const float* __restrict__ y,
    const bf16* __restrict__ wb,
    const float* __restrict__ bq, const float* __restrict__ bk,
    const float* __restrict__ bv,
    bf16* __restrict__ qout, bf16* __restrict__ kout, bf16* __restrict__ vout)
{
    // xT: [2][32 pos][64 bf16]  (128-B rows; 16B-chunk index ^= row&7)
    __shared__ __align__(16) char smem[2*4096];
    bf16* xT  = (bf16*)smem;
    u32*  xTw = (u32*)smem;

    const int t    = threadIdx.x;
    const int lane = t & 63;
    const int w    = t >> 6;
    const int ln   = lane & 15;
    const int quad = lane >> 4;

    const int bid  = blockIdx.x;
    const int dirb = bid & 7;
    const int src  = dirb >> 2;
    const int b    = dirb & 3;
    const int i0   = (bid >> 3) * 32;
    const float* in = src ? y : x;
    const float* xbase = in + (size_t)b*CC*SS + i0;

    const bool stager = (t < 128);
    const int cp = t >> 3;            // cc-pair 0..15 (valid for stagers)
    const int pq = (t & 7) * 4;       // pos 0..28

    float bias[5];
    #pragma unroll
    for (int nbl = 0; nbl < 5; ++nbl) {
        const int o = 80*w + nbl*16 + ln;
        bias[nbl] = (o < 32) ? bq[o] : (o < 64) ? bk[o-32] : bv[o-64];
    }
    f32x4 acc[2][5];
    #pragma unroll
    for (int mb = 0; mb < 2; ++mb)
        #pragma unroll
        for (int nbl = 0; nbl < 5; ++nbl)
            acc[mb][nbl] = (f32x4){bias[nbl], bias[nbl], bias[nbl], bias[nbl]};

    const bf16* wrow = wb + (size_t)(80*w + ln)*CC + quad*8;
    bf16x8 bf[5];
    #pragma unroll
    for (int nbl = 0; nbl < 5; ++nbl)
        bf[nbl] = *(const bf16x8*)(wrow + (size_t)nbl*16*CC);

    float4 a0, a1;
    // stage chunk 0 into buf0, prefetch chunk 1 into regs
    if (stager) {
        const float* r0 = xbase + (size_t)(2*cp)*SS + pq;
        const float4 c0 = *(const float4*)r0;
        const float4 c1 = *(const float4*)(r0 + SS);
        const int chb = cp >> 2, lo = cp & 3;
        xTw[(pq+0)*32 + ((chb ^ ((pq+0)&7)) << 2) + lo] = pack2(c0.x, c1.x);
        xTw[(pq+1)*32 + ((chb ^ ((pq+1)&7)) << 2) + lo] = pack2(c0.y, c1.y);
        xTw[(pq+2)*32 + ((chb ^ ((pq+2)&7)) << 2) + lo] = pack2(c0.z, c1.z);
        xTw[(pq+3)*32 + ((chb ^ ((pq+3)&7)) << 2) + lo] = pack2(c0.w, c1.w);
        const float* r1 = xbase + (size_t)(32 + 2*cp)*SS + pq;
        a0 = *(const float4*)r1;
        a1 = *(const float4*)(r1 + SS);
    }
    __syncthreads();

    const int swz = ln & 7;
    for (int n = 0; n < 8; ++n) {
        bf16x8 af[2];
        #pragma unroll
        for (int mb = 0; mb < 2; ++mb)
            af[mb] = *(const bf16x8*)(xT + (n&1)*2048 + (mb*16 + ln)*64
                                      + ((quad ^ swz) << 3));
        // write prefetched chunk n+1 into other buffer
        if (n < 7 && stager) {
            u32* dst = xTw + ((n+1)&1)*1024;
            const int chb = cp >> 2, lo = cp & 3;
            dst[(pq+0)*32 + ((chb ^ ((pq+0)&7)) << 2) + lo] = pack2(a0.x, a1.x);
            dst[(pq+1)*32 + ((chb ^ ((pq+1)&7)) << 2) + lo] = pack2(a0.y, a1.y);
            dst[(pq+2)*32 + ((chb ^ ((pq+2)&7)) << 2) + lo] = pack2(a0.z, a1.z);
            dst[(pq+3)*32 + ((chb ^ ((pq+3)&7)) << 2) + lo] = pack2(a0.w, a1.w);
        }
        // prefetch chunk n+2 regs (wrap keeps loads in-bounds; redundant at tail)
        if (stager) {
            const int cc2 = ((n+2)*32) & 255;
            const float* r2 = xbase + (size_t)(cc2 + 2*cp)*SS + pq;
            a0 = *(const float4*)r2;
            a1 = *(const float4*)(r2 + SS);
        }
        #pragma unroll
        for (int mb = 0; mb < 2; ++mb)
            #pragma unroll
            for (int nbl = 0; nbl < 5; ++nbl)
                acc[mb][nbl] = __builtin_amdgcn_mfma_f32_16x16x32_bf16(
                                   af[mb], bf[nbl], acc[mb][nbl], 0, 0, 0);
        // prefetch next W chunk
        const int ccn = ((n+1)*32) & 255;
        #pragma unroll
        for (int nbl = 0; nbl < 5; ++nbl)
            bf[nbl] = *(const bf16x8*)(wrow + (size_t)nbl*16*CC + ccn);
        __syncthreads();
    }

    bf16* qo = qout + (size_t)(src*BB + b)*SS*DD;
    bf16* ko = kout + (size_t)(src*BB + b)*SS*DD;
    bf16* vo = vout + (size_t)(src*BB + b)*CC*SS;
    #pragma unroll
    for (int nbl = 0; nbl < 5; ++nbl) {
        const int o = 80*w + nbl*16 + ln;
        if (o < 32) {
            #pragma unroll
            for (int mb = 0; mb < 2; ++mb)
                #pragma unroll
                for (int r = 0; r < 4; ++r)
                    qo[(size_t)(i0 + mb*16 + quad*4 + r)*DD + o] = (bf16)acc[mb][nbl][r];
        } else if (o < 64) {
            #pragma unroll
            for (int mb = 0; mb < 2; ++mb)
                #pragma unroll
                for (int r = 0; r < 4; ++r)
                    ko[(size_t)(i0 + mb*16 + quad*4 + r)*DD + (o-32)] = (bf16)acc[mb][nbl][r];
        } else {
            const int c = o - 64;
            #pragma unroll
            for (int mb = 0; mb < 2; ++mb) {
                bf16x4 pk;
                #pragma unroll
                for (int r = 0; r < 4; ++r) pk[r] = (bf16)acc[mb][nbl][r];
                *(bf16x4*)(vo + (size_t)c*SS + i0 + mb*16 + quad*4) = pk;
            }
        }
    }
}

// ------------------------------------------------- attention (pipelined, S^T)
// Block: 64 queries x 256 c; wave w: S^T for queries [16w,16w+16), PV c-range
// [64w, 64w+64). P in LDS: [2][64 rows][64 bf16] (128-B rows), 16B-chunk index
// XOR-swizzled with row&7 -> conflict-free ds_read_b128 (was 144-B rows, 6.29M
// conflict cycles). V and K fragments double-buffered in regs, loaded 2 chunks
// ahead (L2 latency fully covered). 1 barrier/chunk.
#define SM_M 16.0f

__global__ __launch_bounds__(256, 2) void attn_kernel(
    const bf16* __restrict__ qg, const bf16* __restrict__ kg,
    const bf16* __restrict__ vg, float* __restrict__ out)
{
    __shared__ __align__(16) char smem[16640];
    bf16*  p_s = (bf16*)smem;               // [2][64][64] swizzled
    float* l_s = (float*)(smem + 16384);    // [64]

    const int t    = threadIdx.x;
    const int lane = t & 63;
    const int w    = t >> 6;
    const int ln   = lane & 15;
    const int quad = lane >> 4;

    const int bid  = blockIdx.x;
    const int dirb = bid & 7;
    const int dir  = dirb >> 2;
    const int b    = dirb & 3;
    const int i0   = (bid >> 3) * 64;

    const bf16* q = qg + ((size_t)dir*BB + b)*SS*DD + (size_t)i0*DD;
    const bf16* k = kg + ((size_t)(1-dir)*BB + b)*SS*DD;
    const bf16* v = vg + ((size_t)(1-dir)*BB + b)*CC*SS;
    float* op = out + ((size_t)dir*BB + b)*CC*SS;

    // Q as B-frag: B[n=q(ln)][k=d(quad*8+)]  (wave's 16 queries)
    const bf16x8 b_q = *(const bf16x8*)(q + (size_t)(w*16 + ln)*DD + quad*8);
    // K as A-frag base: A[m=key(ln)][k=d(quad*8+)]
    const bf16* kbase = k + (size_t)ln*DD + quad*8;
    const bf16* vptr[4];
    #pragma unroll
    for (int cb = 0; cb < 4; ++cb)
        vptr[cb] = v + (size_t)(w*64 + cb*16 + ln)*SS + quad*8;

    f32x4 o[4][4];
    #pragma unroll
    for (int qb = 0; qb < 4; ++qb)
        #pragma unroll
        for (int cb = 0; cb < 4; ++cb) o[qb][cb] = (f32x4){0.f,0.f,0.f,0.f};
    float lp = 0.f;

    const int swz  = ln & 7;
    const int prow = (w*16 + ln)*64;

    // double-buffered register fragments (static indexing only — no scratch)
    bf16x8 kfA[4], kfB[4], vfA[2][4], vfB[2][4];
    {
        bf16x8 k0[4];
        #pragma unroll
        for (int nb = 0; nb < 4; ++nb)
            k0[nb]  = *(const bf16x8*)(kbase + (size_t)(nb*16)*DD);
        #pragma unroll
        for (int nb = 0; nb < 4; ++nb)
            kfB[nb] = *(const bf16x8*)(kbase + (size_t)(64  + nb*16)*DD);
        #pragma unroll
        for (int nb = 0; nb < 4; ++nb)
            kfA[nb] = *(const bf16x8*)(kbase + (size_t)(128 + nb*16)*DD);
        #pragma unroll
        for (int ks = 0; ks < 2; ++ks)
            #pragma unroll
            for (int cb = 0; cb < 4; ++cb) {
                vfA[ks][cb] = *(const bf16x8*)(vptr[cb] + ks*32);
                vfB[ks][cb] = *(const bf16x8*)(vptr[cb] + 64 + ks*32);
            }
        // prologue: S^T(0) + softmax(0) -> buf0
        f32x4 s[4];
        #pragma unroll
        for (int nb = 0; nb < 4; ++nb)
            s[nb] = __builtin_amdgcn_mfma_f32_16x16x32_bf16(
                        k0[nb], b_q, (f32x4){0.f,0.f,0.f,0.f}, 0, 0, 0);
        #pragma unroll
        for (int nb = 0; nb < 4; ++nb) {
            bf16x4 pk;
            #pragma unroll
            for (int r = 0; r < 4; ++r) {
                const float e = __expf(fminf(s[nb][r] - SM_M, 60.0f));
                lp += e;
                pk[r] = (bf16)e;
            }
            *(bf16x4*)(p_s + prow + (((2*nb + (quad >> 1)) ^ swz) << 3)
                       + (quad & 1)*4) = pk;
        }
    }

    // iter n: PV(n) from pr/vfc; S^T(n+1) with kfu -> softmax -> pw;
    // reload vfc <- V(n+2), kfu <- K(n+3).
    auto attn_iter = [&](int n, bf16x8 (&vfc)[2][4], bf16x8 (&kfu)[4],
                         const bf16* pr, bf16* pw) {
        __syncthreads();   // P(n) visible; pw buffer free (PV(n-1) done)
        f32x4 s[4];
        if (n < 63) {
            // S^T(n+1): independent of P(n) -> co-issues with PV(n)
            #pragma unroll
            for (int nb = 0; nb < 4; ++nb)
                s[nb] = __builtin_amdgcn_mfma_f32_16x16x32_bf16(
                            kfu[nb], b_q, (f32x4){0.f,0.f,0.f,0.f}, 0, 0, 0);
            const int j3 = ((n + 3) << 6) & (SS - 1);
            #pragma unroll
            for (int nb = 0; nb < 4; ++nb)
                kfu[nb] = *(const bf16x8*)(kbase + (size_t)(j3 + nb*16)*DD);
        }
        // PV(n)
        #pragma unroll
        for (int ks = 0; ks < 2; ++ks) {
            bf16x8 ap[4];
            #pragma unroll
            for (int qb = 0; qb < 4; ++qb)
                ap[qb] = *(const bf16x8*)(pr + (qb*16 + ln)*64
                                          + (((ks*4 + quad) ^ swz) << 3));
            #pragma unroll
            for (int qb = 0; qb < 4; ++qb)
                #pragma unroll
                for (int cb = 0; cb < 4; ++cb)
                    o[qb][cb] = __builtin_amdgcn_mfma_f32_16x16x32_bf16(
                                    ap[qb], vfc[ks][cb], o[qb][cb], 0, 0, 0);
        }
        // V(n+2) into the slot just consumed (used 2 iters ahead)
        const int j2 = ((n + 2) << 6) & (SS - 1);
        #pragma unroll
        for (int ks = 0; ks < 2; ++ks)
            #pragma unroll
            for (int cb = 0; cb < 4; ++cb)
                vfc[ks][cb] = *(const bf16x8*)(vptr[cb] + j2 + ks*32);
        if (n < 63) {
            // softmax(n+1) -> pw (S-mfma results long ready)
            #pragma unroll
            for (int nb = 0; nb < 4; ++nb) {
                bf16x4 pk;
                #pragma unroll
                for (int r = 0; r < 4; ++r) {
                    const float e = __expf(fminf(s[nb][r] - SM_M, 60.0f));
                    lp += e;
                    pk[r] = (bf16)e;
                }
                *(bf16x4*)(pw + prow + (((2*nb + (quad >> 1)) ^ swz) << 3)
                           + (quad & 1)*4) = pk;
            }
        }
    };

    for (int n = 0; n < 64; n += 2) {
        attn_iter(n,     vfA, kfB, p_s,        p_s + 4096);
        attn_iter(n + 1, vfB, kfA, p_s + 4096, p_s);
    }

    // l: lane covers keys {*, nb*16+quad*4+r} for query w*16+ln -> reduce quads
    lp += __shfl_xor(lp, 16);
    lp += __shfl_xor(lp, 32);
    if (lane < 16) l_s[w*16 + ln] = lp;
    __syncthreads();

    // epilogue: normalize + direct coalesced stores
    #pragma unroll
    for (int qb = 0; qb < 4; ++qb) {
        const f32x4 lq = *(const f32x4*)(l_s + qb*16 + quad*4);
        const float ri0 = 1.0f/lq[0], ri1 = 1.0f/lq[1], ri2 = 1.0f/lq[2], ri3 = 1.0f/lq[3];
        #pragma unroll
        for (int cb = 0; cb < 4; ++cb) {
            const int c = w*64 + cb*16 + ln;
            float4 val = make_float4(o[qb][cb][0]*ri0, o[qb][cb][1]*ri1,
                                     o[qb][cb][2]*ri2, o[qb][cb][3]*ri3);
            *(float4*)(op + (size_t)c*SS + i0 + qb*16 + quad*4) = val;
        }
    }
}

// ------------------------------------------------- launch
extern "C" void kernel_launch(void* const* d_in, const int* in_sizes, int n_in,
                              void* d_out, int out_size, void* d_ws, size_t ws_size,
                              hipStream_t stream)
{
    const float* x  = (const float*)d_in[0];
    const float* y  = (const float*)d_in[1];
    const float* Wq = (const float*)d_in[2];
    const float* bq = (const float*)d_in[3];
    const float* Wk = (const float*)d_in[4];
    const float* bk = (const float*)d_in[5];
    const float* Wv = (const float*)d_in[6];
    const float* bv = (const float*)d_in[7];
    float* out = (float*)d_out;
    bf16* ws   = (bf16*)d_ws;

    bf16* qw = ws + Q_OFF;
    bf16* kw = ws + K_OFF;
    bf16* vw = ws + V_OFF;
    bf16* wb = ws + WB_OFF;

    convert_w_kernel<<<40,   256, 0, stream>>>(Wq, Wk, Wv, wb);
    proj_all_kernel <<<1024, 256, 0, stream>>>(x, y, wb, bq, bk, bv, qw, kw, vw);
    attn_kernel     <<<512,  256, 0, stream>>>(qw, kw, vw, out);
}

// Round 2
// 255.367 us; speedup vs baseline: 1.0686x; 1.0686x over previous
//
#include <hip/hip_runtime.h>

#define BB 4
#define CC 256
#define DD 32
#define SS 4096

typedef __bf16 bf16;
typedef __bf16 bf16x8 __attribute__((ext_vector_type(8)));
typedef __bf16 bf16x4 __attribute__((ext_vector_type(4)));
typedef float f32x4 __attribute__((ext_vector_type(4)));
typedef unsigned int u32;
typedef unsigned short u16;

// workspace layout (bf16 elements):
//  q:  [2][BB][SS][DD]  off 0         (pos-major, 32 d inner)
//  k:  [2][BB][SS][DD]  off 1048576
//  v:  [2][BB][CC][SS]  off 2097152   (c-major, pos inner)
//  wb: [320][CC]        off 10485760  (bf16 Wq|Wk|Wv stacked)
#define Q_OFF  0
#define K_OFF  1048576
#define V_OFF  2097152
#define WB_OFF 10485760

static __device__ __forceinline__ u32 pack2(float lo, float hi) {
    bf16 a = (bf16)lo, b = (bf16)hi;
    u16 ua = __builtin_bit_cast(u16, a), ub = __builtin_bit_cast(u16, b);
    return (u32)ua | ((u32)ub << 16);
}

// LDS-only barrier: drain ds ops, sync, but let global loads stay in flight
// (__syncthreads emits s_waitcnt vmcnt(0) which defeats register prefetch).
static __device__ __forceinline__ void bar_lds() {
    asm volatile("s_waitcnt lgkmcnt(0)" ::: "memory");
    __builtin_amdgcn_s_barrier();
    asm volatile("" ::: "memory");
}

// ------------------------------------------------- W fp32 -> bf16 [320][256]
__global__ __launch_bounds__(256) void convert_w_kernel(
    const float* __restrict__ Wq, const float* __restrict__ Wk,
    const float* __restrict__ Wv, bf16* __restrict__ wb)
{
    const int gid = blockIdx.x*256 + threadIdx.x;    // 40 blocks -> 10240
    const int idx = gid*8;
    const int o = idx >> 8, cc = idx & 255;
    const float* row = (o < 32) ? (Wq + (size_t)o*CC)
                     : (o < 64) ? (Wk + (size_t)(o-32)*CC)
                                : (Wv + (size_t)(o-64)*CC);
    const float4 a = *(const float4*)(row + cc);
    const float4 c = *(const float4*)(row + cc + 4);
    bf16x8 pk;
    pk[0]=(bf16)a.x; pk[1]=(bf16)a.y; pk[2]=(bf16)a.z; pk[3]=(bf16)a.w;
    pk[4]=(bf16)c.x; pk[5]=(bf16)c.y; pk[6]=(bf16)c.z; pk[7]=(bf16)c.w;
    *(bf16x8*)(wb + idx) = pk;
}

// ------------------------------------------------- fused q,k,v projection (MFMA)
// C[pos][o] = sum_cc X[cc][pos]*W[o][cc] + bias;  o: 0-31 q, 32-63 k, 64-319 v
// Double-buffered xT + register X-prefetch; bar_lds (no vmcnt drain) keeps the
// global prefetches in flight across the per-chunk barrier.
__global__ __launch_bounds__(256, 2) void proj_all_kernel(
    const float* __restrict__ x, const float* __restrict__ y,
    const bf16* __restrict__ wb,
    const float* __restrict__ bq, const float* __restrict__ bk,
    const float* __restrict__ bv,
    bf16* __restrict__ qout, bf16* __restrict__ kout, bf16* __restrict__ vout)
{
    // xT: [2][64 pos][40 bf16] (row 80 B, 16B-aligned)
    __shared__ __align__(16) char smem[2*5120];
    bf16* xT  = (bf16*)smem;
    u32*  xTw = (u32*)smem;

    const int t    = threadIdx.x;
    const int lane = t & 63;
    const int w    = t >> 6;
    const int ln   = lane & 15;
    const int quad = lane >> 4;

    const int bid  = blockIdx.x;
    const int dirb = bid & 7;
    const int src  = dirb >> 2;
    const int b    = dirb & 3;
    const int i0   = (bid >> 3) * 64;
    const float* in = src ? y : x;
    const float* xbase = in + (size_t)b*CC*SS + i0;

    const int cp = t >> 4;            // cc-pair 0..15 -> cc {2cp, 2cp+1}
    const int pq = (t & 15) * 4;      // pos 0..60

    float bias[5];
    #pragma unroll
    for (int nbl = 0; nbl < 5; ++nbl) {
        const int o = 80*w + nbl*16 + ln;
        bias[nbl] = (o < 32) ? bq[o] : (o < 64) ? bk[o-32] : bv[o-64];
    }
    f32x4 acc[4][5];
    #pragma unroll
    for (int mb = 0; mb < 4; ++mb)
        #pragma unroll
        for (int nbl = 0; nbl < 5; ++nbl)
            acc[mb][nbl] = (f32x4){bias[nbl], bias[nbl], bias[nbl], bias[nbl]};

    const bf16* wrow = wb + (size_t)(80*w + ln)*CC + quad*8;
    bf16x8 bf[5];
    #pragma unroll
    for (int nbl = 0; nbl < 5; ++nbl)
        bf[nbl] = *(const bf16x8*)(wrow + (size_t)nbl*16*CC);

    // stage chunk 0 into buf0
    {
        const float* r0 = xbase + (size_t)(2*cp)*SS + pq;
        const float4 a0 = *(const float4*)r0;
        const float4 a1 = *(const float4*)(r0 + SS);
        xTw[(pq+0)*20 + cp] = pack2(a0.x, a1.x);
        xTw[(pq+1)*20 + cp] = pack2(a0.y, a1.y);
        xTw[(pq+2)*20 + cp] = pack2(a0.z, a1.z);
        xTw[(pq+3)*20 + cp] = pack2(a0.w, a1.w);
    }
    // prefetch chunk 1 into regs
    float4 a0, a1;
    {
        const float* r1 = xbase + (size_t)(32 + 2*cp)*SS + pq;
        a0 = *(const float4*)r1;
        a1 = *(const float4*)(r1 + SS);
    }
    bar_lds();

    for (int n = 0; n < 8; ++n) {
        bf16x8 af[4];
        #pragma unroll
        for (int mb = 0; mb < 4; ++mb)
            af[mb] = *(const bf16x8*)(xT + (n&1)*2560 + (mb*16 + ln)*40 + quad*8);
        // write prefetched chunk n+1 into other buffer
        if (n < 7) {
            u32* dst = xTw + ((n+1)&1)*1280;
            dst[(pq+0)*20 + cp] = pack2(a0.x, a1.x);
            dst[(pq+1)*20 + cp] = pack2(a0.y, a1.y);
            dst[(pq+2)*20 + cp] = pack2(a0.z, a1.z);
            dst[(pq+3)*20 + cp] = pack2(a0.w, a1.w);
        }
        // prefetch chunk n+2 regs (wrap keeps loads in-bounds; redundant at tail)
        {
            const int cc2 = ((n+2)*32) & 255;
            const float* r2 = xbase + (size_t)(cc2 + 2*cp)*SS + pq;
            a0 = *(const float4*)r2;
            a1 = *(const float4*)(r2 + SS);
        }
        #pragma unroll
        for (int mb = 0; mb < 4; ++mb)
            #pragma unroll
            for (int nbl = 0; nbl < 5; ++nbl)
                acc[mb][nbl] = __builtin_amdgcn_mfma_f32_16x16x32_bf16(
                                   af[mb], bf[nbl], acc[mb][nbl], 0, 0, 0);
        // prefetch next W chunk
        const int ccn = ((n+1)*32) & 255;
        #pragma unroll
        for (int nbl = 0; nbl < 5; ++nbl)
            bf[nbl] = *(const bf16x8*)(wrow + (size_t)nbl*16*CC + ccn);
        bar_lds();
    }

    bf16* qo = qout + (size_t)(src*BB + b)*SS*DD;
    bf16* ko = kout + (size_t)(src*BB + b)*SS*DD;
    bf16* vo = vout + (size_t)(src*BB + b)*CC*SS;
    #pragma unroll
    for (int nbl = 0; nbl < 5; ++nbl) {
        const int o = 80*w + nbl*16 + ln;
        if (o < 32) {
            #pragma unroll
            for (int mb = 0; mb < 4; ++mb)
                #pragma unroll
                for (int r = 0; r < 4; ++r)
                    qo[(size_t)(i0 + mb*16 + quad*4 + r)*DD + o] = (bf16)acc[mb][nbl][r];
        } else if (o < 64) {
            #pragma unroll
            for (int mb = 0; mb < 4; ++mb)
                #pragma unroll
                for (int r = 0; r < 4; ++r)
                    ko[(size_t)(i0 + mb*16 + quad*4 + r)*DD + (o-32)] = (bf16)acc[mb][nbl][r];
        } else {
            const int c = o - 64;
            #pragma unroll
            for (int mb = 0; mb < 4; ++mb) {
                bf16x4 pk;
                #pragma unroll
                for (int r = 0; r < 4; ++r) pk[r] = (bf16)acc[mb][nbl][r];
                *(bf16x4*)(vo + (size_t)c*SS + i0 + mb*16 + quad*4) = pk;
            }
        }
    }
}

// ------------------------------------------------- attention (pipelined, S^T)
// Block: 64 queries x 256 c; wave w: S^T for queries [16w,16w+16), PV c-range
// [64w, 64w+64). P in LDS: [2][64 rows][64 bf16] (128-B rows), 16B-chunk index
// XOR-swizzled with row&7. V and K fragments double-buffered in regs, loaded
// 2/3 chunks ahead; bar_lds (lgkmcnt-only) keeps them in flight across the
// per-chunk barrier (__syncthreads' vmcnt(0) drain was serializing L2 latency
// every iteration). lp accumulated in 4 independent slots (breaks the 16-deep
// serial add chain).
#define SM_M 16.0f

__global__ __launch_bounds__(256, 2) void attn_kernel(
    const bf16* __restrict__ qg, const bf16* __restrict__ kg,
    const bf16* __restrict__ vg, float* __restrict__ out)
{
    __shared__ __align__(16) char smem[16640];
    bf16*  p_s = (bf16*)smem;               // [2][64][64] swizzled
    float* l_s = (float*)(smem + 16384);    // [64]

    const int t    = threadIdx.x;
    const int lane = t & 63;
    const int w    = t >> 6;
    const int ln   = lane & 15;
    const int quad = lane >> 4;

    const int bid  = blockIdx.x;
    const int dirb = bid & 7;
    const int dir  = dirb >> 2;
    const int b    = dirb & 3;
    const int i0   = (bid >> 3) * 64;

    const bf16* q = qg + ((size_t)dir*BB + b)*SS*DD + (size_t)i0*DD;
    const bf16* k = kg + ((size_t)(1-dir)*BB + b)*SS*DD;
    const bf16* v = vg + ((size_t)(1-dir)*BB + b)*CC*SS;
    float* op = out + ((size_t)dir*BB + b)*CC*SS;

    // Q as B-frag: B[n=q(ln)][k=d(quad*8+)]  (wave's 16 queries)
    const bf16x8 b_q = *(const bf16x8*)(q + (size_t)(w*16 + ln)*DD + quad*8);
    // K as A-frag base: A[m=key(ln)][k=d(quad*8+)]
    const bf16* kbase = k + (size_t)ln*DD + quad*8;
    const bf16* vptr[4];
    #pragma unroll
    for (int cb = 0; cb < 4; ++cb)
        vptr[cb] = v + (size_t)(w*64 + cb*16 + ln)*SS + quad*8;

    f32x4 o[4][4];
    #pragma unroll
    for (int qb = 0; qb < 4; ++qb)
        #pragma unroll
        for (int cb = 0; cb < 4; ++cb) o[qb][cb] = (f32x4){0.f,0.f,0.f,0.f};
    f32x4 lpv = (f32x4){0.f,0.f,0.f,0.f};

    const int swz  = ln & 7;
    const int prow = (w*16 + ln)*64;

    // double-buffered register fragments (static indexing only — no scratch)
    bf16x8 kfA[4], kfB[4], vfA[2][4], vfB[2][4];
    {
        bf16x8 k0[4];
        #pragma unroll
        for (int nb = 0; nb < 4; ++nb)
            k0[nb]  = *(const bf16x8*)(kbase + (size_t)(nb*16)*DD);
        #pragma unroll
        for (int nb = 0; nb < 4; ++nb)
            kfB[nb] = *(const bf16x8*)(kbase + (size_t)(64  + nb*16)*DD);
        #pragma unroll
        for (int nb = 0; nb < 4; ++nb)
            kfA[nb] = *(const bf16x8*)(kbase + (size_t)(128 + nb*16)*DD);
        #pragma unroll
        for (int ks = 0; ks < 2; ++ks)
            #pragma unroll
            for (int cb = 0; cb < 4; ++cb) {
                vfA[ks][cb] = *(const bf16x8*)(vptr[cb] + ks*32);
                vfB[ks][cb] = *(const bf16x8*)(vptr[cb] + 64 + ks*32);
            }
        // prologue: S^T(0) + softmax(0) -> buf0
        f32x4 s[4];
        #pragma unroll
        for (int nb = 0; nb < 4; ++nb)
            s[nb] = __builtin_amdgcn_mfma_f32_16x16x32_bf16(
                        k0[nb], b_q, (f32x4){0.f,0.f,0.f,0.f}, 0, 0, 0);
        #pragma unroll
        for (int nb = 0; nb < 4; ++nb) {
            bf16x4 pk;
            #pragma unroll
            for (int r = 0; r < 4; ++r) {
                const float e = __expf(fminf(s[nb][r] - SM_M, 60.0f));
                lpv[r] += e;
                pk[r] = (bf16)e;
            }
            *(bf16x4*)(p_s + prow + (((2*nb + (quad >> 1)) ^ swz) << 3)
                       + (quad & 1)*4) = pk;
        }
    }

    // iter n: PV(n) from pr/vfc; S^T(n+1) with kfu -> softmax -> pw;
    // reload vfc <- V(n+2), kfu <- K(n+3).
    auto attn_iter = [&](int n, bf16x8 (&vfc)[2][4], bf16x8 (&kfu)[4],
                         const bf16* pr, bf16* pw) {
        bar_lds();   // P(n) visible; pw buffer free (PV(n-1) done)
        f32x4 s[4];
        if (n < 63) {
            // S^T(n+1): independent of P(n) -> co-issues with PV(n)
            #pragma unroll
            for (int nb = 0; nb < 4; ++nb)
                s[nb] = __builtin_amdgcn_mfma_f32_16x16x32_bf16(
                            kfu[nb], b_q, (f32x4){0.f,0.f,0.f,0.f}, 0, 0, 0);
            const int j3 = ((n + 3) << 6) & (SS - 1);
            #pragma unroll
            for (int nb = 0; nb < 4; ++nb)
                kfu[nb] = *(const bf16x8*)(kbase + (size_t)(j3 + nb*16)*DD);
        }
        // PV(n)
        #pragma unroll
        for (int ks = 0; ks < 2; ++ks) {
            bf16x8 ap[4];
            #pragma unroll
            for (int qb = 0; qb < 4; ++qb)
                ap[qb] = *(const bf16x8*)(pr + (qb*16 + ln)*64
                                          + (((ks*4 + quad) ^ swz) << 3));
            #pragma unroll
            for (int qb = 0; qb < 4; ++qb)
                #pragma unroll
                for (int cb = 0; cb < 4; ++cb)
                    o[qb][cb] = __builtin_amdgcn_mfma_f32_16x16x32_bf16(
                                    ap[qb], vfc[ks][cb], o[qb][cb], 0, 0, 0);
        }
        // V(n+2) into the slot just consumed (used 2 iters ahead)
        const int j2 = ((n + 2) << 6) & (SS - 1);
        #pragma unroll
        for (int ks = 0; ks < 2; ++ks)
            #pragma unroll
            for (int cb = 0; cb < 4; ++cb)
                vfc[ks][cb] = *(const bf16x8*)(vptr[cb] + j2 + ks*32);
        if (n < 63) {
            // softmax(n+1) -> pw (S-mfma results long ready)
            #pragma unroll
            for (int nb = 0; nb < 4; ++nb) {
                bf16x4 pk;
                #pragma unroll
                for (int r = 0; r < 4; ++r) {
                    const float e = __expf(fminf(s[nb][r] - SM_M, 60.0f));
                    lpv[r] += e;
                    pk[r] = (bf16)e;
                }
                *(bf16x4*)(pw + prow + (((2*nb + (quad >> 1)) ^ swz) << 3)
                           + (quad & 1)*4) = pk;
            }
        }
    };

    for (int n = 0; n < 64; n += 2) {
        attn_iter(n,     vfA, kfB, p_s,        p_s + 4096);
        attn_iter(n + 1, vfB, kfA, p_s + 4096, p_s);
    }

    // l: lane covers keys {*, nb*16+quad*4+r} for query w*16+ln -> reduce quads
    float lp = (lpv[0] + lpv[1]) + (lpv[2] + lpv[3]);
    lp += __shfl_xor(lp, 16);
    lp += __shfl_xor(lp, 32);
    if (lane < 16) l_s[w*16 + ln] = lp;
    __syncthreads();

    // epilogue: normalize + direct coalesced stores
    #pragma unroll
    for (int qb = 0; qb < 4; ++qb) {
        const f32x4 lq = *(const f32x4*)(l_s + qb*16 + quad*4);
        const float ri0 = 1.0f/lq[0], ri1 = 1.0f/lq[1], ri2 = 1.0f/lq[2], ri3 = 1.0f/lq[3];
        #pragma unroll
        for (int cb = 0; cb < 4; ++cb) {
            const int c = w*64 + cb*16 + ln;
            float4 val = make_float4(o[qb][cb][0]*ri0, o[qb][cb][1]*ri1,
                                     o[qb][cb][2]*ri2, o[qb][cb][3]*ri3);
            *(float4*)(op + (size_t)c*SS + i0 + qb*16 + quad*4) = val;
        }
    }
}

// ------------------------------------------------- launch
extern "C" void kernel_launch(void* const* d_in, const int* in_sizes, int n_in,
                              void* d_out, int out_size, void* d_ws, size_t ws_size,
                              hipStream_t stream)
{
    const float* x  = (const float*)d_in[0];
    const float* y  = (const float*)d_in[1];
    const float* Wq = (const float*)d_in[2];
    const float* bq = (const float*)d_in[3];
    const float* Wk = (const float*)d_in[4];
    const float* bk = (const float*)d_in[5];
    const float* Wv = (const float*)d_in[6];
    const float* bv = (const float*)d_in[7];
    float* out = (float*)d_out;
    bf16* ws   = (bf16*)d_ws;

    bf16* qw = ws + Q_OFF;
    bf16* kw = ws + K_OFF;
    bf16* vw = ws + V_OFF;
    bf16* wb = ws + WB_OFF;

    convert_w_kernel<<<40,  256, 0, stream>>>(Wq, Wk, Wv, wb);
    proj_all_kernel <<<512, 256, 0, stream>>>(x, y, wb, bq, bk, bv, qw, kw, vw);
    attn_kernel     <<<512, 256, 0, stream>>>(qw, kw, vw, out);
}